// Round 5
// baseline (198.461 us; speedup 1.0000x reference)
//
#include <hip/hip_runtime.h>
#include <hip/hip_bf16.h>
#include <math.h>

typedef unsigned short u16;
typedef __attribute__((ext_vector_type(8))) short bf16x8;
typedef __attribute__((ext_vector_type(4))) float f32x4;

constexpr int D_ = 1024;
constexpr int H_ = 1365;
constexpr int E_ = 7;
constexpr int NTOK = 2048;
constexpr int HP = 1408;          // H padded to multiple of 64
constexpr int NE = 8;             // 7 routed + 1 shared
constexpr int SHARED_BASE = 4096;
constexpr int SLOTS = 6144;

#define CI_COUNT 0
#define CI_OFF   8

constexpr size_t WS_CTRL = 0;
constexpr size_t WS_TIDX = 256;
constexpr size_t WS_TW   = WS_TIDX + (size_t)NTOK*2*4;
constexpr size_t WS_PROB = WS_TW   + (size_t)NTOK*2*4;
constexpr size_t WS_LSE2 = WS_PROB + (size_t)NTOK*8*4;
constexpr size_t WS_STOK = WS_LSE2 + (size_t)NTOK*4;
constexpr size_t WS_SW   = WS_STOK + (size_t)SLOTS*4;
constexpr size_t WS_TSL  = WS_SW   + (size_t)SLOTS*4;
constexpr size_t WS_B1   = WS_TSL  + (size_t)NTOK*2*4;
constexpr size_t WS_B2   = WS_B1   + (size_t)NE*H_*4;
constexpr size_t WS_XB   = ((WS_B2 + (size_t)NE*D_*4) + 255) & ~(size_t)255;
constexpr size_t WS_W1B  = WS_XB  + (size_t)NTOK*D_*2;
constexpr size_t WS_W2B  = WS_W1B + (size_t)NE*H_*D_*2;
constexpr size_t WS_HEB  = WS_W2B + (size_t)NE*D_*HP*2;
constexpr size_t WS_Y    = WS_XB;   // y[SLOTS][D] fp32 aliases xb+w1b (dead after gemm1)

__device__ __forceinline__ u16 f2bf(float f) {
    __hip_bfloat16 h = __float2bfloat16(f);
    return __builtin_bit_cast(u16, h);
}

__device__ __forceinline__ void gload_lds16(const u16* g, u16* l) {
    __builtin_amdgcn_global_load_lds(
        (const __attribute__((address_space(1))) void*)g,
        (__attribute__((address_space(3))) void*)l, 16, 0, 0);
}

__device__ __forceinline__ uint4 pack8(float4 a, float4 b) {
    union { u16 h[8]; uint4 v; } u;
    u.h[0]=f2bf(a.x); u.h[1]=f2bf(a.y); u.h[2]=f2bf(a.z); u.h[3]=f2bf(a.w);
    u.h[4]=f2bf(b.x); u.h[5]=f2bf(b.y); u.h[6]=f2bf(b.z); u.h[7]=f2bf(b.w);
    return u.v;
}

// tanh-form GELU (|err| ~3e-3 abs, below bf16 quantization of He)
__device__ __forceinline__ float fast_gelu(float v) {
    float u = 0.7978845608f * v * (1.f + 0.044715f * v * v);
    float e = __expf(2.f * u);
    float t = 1.f - 2.f / (e + 1.f);   // tanh(u), safe at e=inf
    return 0.5f * v * (1.f + t);
}

// ---------------- convert fp32 -> bf16 staging (weights + biases only) ----------------
__global__ void convert_kernel(const float* __restrict__ W1, const float* __restrict__ Ws1,
                               const float* __restrict__ W2, const float* __restrict__ Ws2,
                               const float* __restrict__ b1, const float* __restrict__ bs1,
                               const float* __restrict__ b2, const float* __restrict__ bs2,
                               u16* __restrict__ w1b, u16* __restrict__ w2b,
                               float* __restrict__ b1all, float* __restrict__ b2all)
{
    const size_t G1 = (size_t)NE*H_*D_/8;
    const size_t G2 = (size_t)NE*D_*HP/8;
    const size_t W1FLAT = (size_t)7*H_*D_;
    const size_t total = G1+G2+(size_t)NE*H_+(size_t)NE*D_;
    for (size_t i = blockIdx.x*(size_t)blockDim.x + threadIdx.x; i < total;
         i += (size_t)gridDim.x*blockDim.x) {
        size_t k = i;
        if (k < G1) {
            size_t base = k*8;
            const float* src = (base < W1FLAT) ? (W1 + base) : (Ws1 + (base - W1FLAT));
            const float4* s = (const float4*)src;
            ((uint4*)w1b)[k] = pack8(s[0], s[1]);
            continue;
        }
        k -= G1;
        if (k < G2) {
            size_t base = k*8;
            size_t e = base/((size_t)D_*HP);
            size_t rr = base - e*(size_t)D_*HP;
            size_t drow = rr/HP, h0 = rr - drow*HP;
            const float* srow = (e < 7) ? (W2 + ((size_t)e*D_ + drow)*H_)
                                        : (Ws2 + drow*(size_t)H_);
            union { u16 h[8]; uint4 v; } u;
            #pragma unroll
            for (int q = 0; q < 8; q++) {
                size_t h = h0 + q;
                u.h[q] = (h < (size_t)H_) ? f2bf(srow[h]) : (u16)0;
            }
            ((uint4*)w2b)[k] = u.v;
            continue;
        }
        k -= G2;
        if (k < (size_t)NE*H_) {
            size_t e = k/H_, j = k - e*H_;
            b1all[k] = (e < 7) ? b1[k] : bs1[j];
        } else {
            size_t kk = k - (size_t)NE*H_;
            size_t e = kk/D_, j = kk - e*D_;
            b2all[kk] = (e < 7) ? b2[kk] : bs2[j];
        }
    }
}

// ---------------- router (+ fused x->bf16) ----------------
__global__ void router_kernel(const float* __restrict__ x, const float* __restrict__ Wg,
                              int* __restrict__ tidx, float* __restrict__ tw,
                              float* __restrict__ probs, float* __restrict__ lse2,
                              u16* __restrict__ xb)
{
    int wid = threadIdx.x >> 6, lane = threadIdx.x & 63;
    int n = blockIdx.x*4 + wid;
    if (n >= NTOK) return;
    float p[E_] = {};
    const float* xr = x + (size_t)n*D_;
    u16* xbr = xb + (size_t)n*D_;
    #pragma unroll
    for (int j = 0; j < 4; j++) {
        int d0 = lane*4 + j*256;
        float4 xv = *(const float4*)(xr + d0);
        ushort4 h;
        h.x = f2bf(xv.x); h.y = f2bf(xv.y); h.z = f2bf(xv.z); h.w = f2bf(xv.w);
        *(ushort4*)(xbr + d0) = h;
        #pragma unroll
        for (int e = 0; e < E_; e++) {
            float4 wv = *(const float4*)(Wg + e*D_ + d0);
            p[e] += xv.x*wv.x + xv.y*wv.y + xv.z*wv.z + xv.w*wv.w;
        }
    }
    #pragma unroll
    for (int e = 0; e < E_; e++) {
        float v = p[e];
        #pragma unroll
        for (int m = 32; m >= 1; m >>= 1) v += __shfl_xor(v, m);
        p[e] = v;
    }
    if (lane == 0) {
        float mx = p[0];
        #pragma unroll
        for (int e = 1; e < E_; e++) mx = fmaxf(mx, p[e]);
        float pr[E_], sum = 0.f;
        #pragma unroll
        for (int e = 0; e < E_; e++) { pr[e] = __expf(p[e]-mx); sum += pr[e]; }
        float lse = mx + logf(sum);
        int i0 = 0;
        #pragma unroll
        for (int e = 1; e < E_; e++) if (p[e] > p[i0]) i0 = e;
        int i1 = -1;
        #pragma unroll
        for (int e = 0; e < E_; e++) if (e != i0 && (i1 < 0 || p[e] > p[i1])) i1 = e;
        float g = expf(p[i1] - p[i0]);
        tidx[n*2] = i0; tidx[n*2+1] = i1;
        tw[n*2] = 1.f/(1.f+g); tw[n*2+1] = g/(1.f+g);
        float inv = 1.f/sum;
        #pragma unroll
        for (int e = 0; e < E_; e++) probs[n*8+e] = pr[e]*inv;
        lse2[n] = lse*lse;
    }
}

// ---------------- finalize: counts, offsets, loss, deterministic scatter ----------------
__global__ __launch_bounds__(512) void finalize_kernel(
    const int* __restrict__ tidx, const float* __restrict__ tw,
    const float* __restrict__ probs, const float* __restrict__ lse2,
    int* __restrict__ ci, int* __restrict__ stok, float* __restrict__ sw,
    int* __restrict__ tsl, float* __restrict__ out)
{
    __shared__ int lt[NTOK*2];
    __shared__ float psum[8];
    __shared__ float lsumS;
    __shared__ int cntS[8], offS[8];
    int t = threadIdx.x;
    if (t < 8) { psum[t] = 0.f; cntS[t] = 0; }
    if (t == 0) lsumS = 0.f;
    for (int i = t; i < NTOK*2; i += 512) lt[i] = tidx[i];
    __syncthreads();
    float lp[E_] = {}; float ll = 0.f;
    for (int n = t; n < NTOK; n += 512) {
        #pragma unroll
        for (int e = 0; e < E_; e++) lp[e] += probs[n*8+e];
        ll += lse2[n];
    }
    #pragma unroll
    for (int e = 0; e < E_; e++) atomicAdd(&psum[e], lp[e]);
    atomicAdd(&lsumS, ll);
    int wid = t >> 6, lane = t & 63;
    if (wid < 7) {
        int c = 0;
        for (int i = lane; i < NTOK*2; i += 64) c += (lt[i] == wid) ? 1 : 0;
        #pragma unroll
        for (int m = 32; m >= 1; m >>= 1) c += __shfl_xor(c, m);
        if (lane == 0) cntS[wid] = c;
    }
    __syncthreads();
    if (t == 0) {
        int o = 0;
        for (int e = 0; e < E_; e++) { offS[e] = o; o += cntS[e]; }
        offS[7] = SHARED_BASE; cntS[7] = NTOK;
        float la = 0.f;
        for (int e = 0; e < E_; e++)
            la += ((float)cntS[e] / (float)(NTOK*2)) * (psum[e] / (float)NTOK);
        out[(size_t)NTOK*D_]     = 0.01f * 7.f * la;
        out[(size_t)NTOK*D_ + 1] = 0.001f * lsumS / (float)NTOK;
        #pragma unroll
        for (int e = 0; e < 8; e++) { ci[CI_COUNT+e] = cntS[e]; ci[CI_OFF+e] = offS[e]; }
    }
    __syncthreads();
    if (wid < 7) {
        int base = offS[wid], run = 0;
        for (int c0 = 0; c0 < NTOK*2; c0 += 64) {
            bool m = (lt[c0 + lane] == wid);
            unsigned long long bal = __ballot(m);
            int pre = __popcll(bal & ((1ull << lane) - 1ull));
            if (m) {
                int i = c0 + lane;
                int s = base + run + pre;
                stok[s] = i >> 1; sw[s] = tw[i]; tsl[i] = s;
            }
            run += __popcll(bal);
        }
    } else {
        for (int n = lane; n < NTOK; n += 64) {
            stok[SHARED_BASE+n] = n; sw[SHARED_BASE+n] = 1.f;
        }
    }
}

// ---------------- GEMMs: 128x64 tile, BK=32, 4-buffer prefetch-3, XCD-pinned ----------------
#define BM 128
#define BN 64
#define BK 32
#define ASZ (BM*BK)   // 4096 elems (8 KiB)
#define BSZ (BN*BK)   // 2048 elems (4 KiB)

__global__ __launch_bounds__(256, 3) void gemm1_kernel(
    const u16* __restrict__ xb, const u16* __restrict__ w1b,
    const float* __restrict__ b1all,
    const int* __restrict__ ci, const int* __restrict__ stok,
    u16* __restrict__ heb)
{
    __shared__ u16 As[4*ASZ];
    __shared__ u16 Bs[4*BSZ];
    int x = blockIdx.x, yb = blockIdx.y;
    int e, mt, nt;
    if (yb < 16*22) {
        if (x == 7) return;
        e = x; mt = yb/22; nt = yb - mt*22;
    } else {
        e = 7; int yy = yb - 16*22; int s = yy/22; nt = yy - s*22; mt = x*2 + s;
    }
    int count = ci[CI_COUNT+e];
    int m0 = mt*BM;
    if (m0 >= count) return;
    int offset = ci[CI_OFF+e];
    int valid = min(BM, count - m0);

    int t = threadIdx.x, wid = t >> 6, lane = t & 63;
    int rl = lane >> 2;
    int sw = (rl ^ (rl >> 2)) & 3;
    int sc = (lane & 3) ^ sw;               // pre-swizzled source chunk
    const u16* w1e = w1b + (size_t)e*H_*D_;

    int r0 = wid*32 + rl;
    int ar0 = min(r0, valid-1), ar1 = min(r0+16, valid-1);
    const u16* aSrc0 = xb + (size_t)stok[offset+m0+ar0]*D_ + sc*8;
    const u16* aSrc1 = xb + (size_t)stok[offset+m0+ar1]*D_ + sc*8;
    int rb = wid*16 + rl;
    int jgB = min(nt*BN + rb, H_-1);
    const u16* bSrc = w1e + (size_t)jgB*D_ + sc*8;
    u16* aD0 = &As[wid*1024];
    u16* aD1 = &As[wid*1024 + 512];
    u16* bD  = &Bs[wid*512];

    int wm = (wid >> 1)*64, wn = (wid & 1)*32;
    int frow = lane & 15, kgrp = lane >> 4;
    int cc = (kgrp ^ ((frow ^ (frow >> 2)) & 3)) * 8;
    f32x4 acc[4][2] = {};

#define STAGE1(tt) do { int _b=((tt)&3); int _ko=(tt)*BK; \
    gload_lds16(aSrc0+_ko, aD0+_b*ASZ); \
    gload_lds16(aSrc1+_ko, aD1+_b*ASZ); \
    gload_lds16(bSrc +_ko, bD +_b*BSZ); } while(0)

    STAGE1(0); STAGE1(1); STAGE1(2);
    constexpr int nIter = D_/BK;          // 32
    for (int tt = 0; tt < nIter; ++tt) {
        if (tt + 3 < nIter) {
            STAGE1(tt+3);
            asm volatile("s_waitcnt vmcnt(9)" ::: "memory");
        } else if (tt + 3 == nIter) {
            asm volatile("s_waitcnt vmcnt(6)" ::: "memory");
        } else if (tt + 2 == nIter) {
            asm volatile("s_waitcnt vmcnt(3)" ::: "memory");
        } else {
            asm volatile("s_waitcnt vmcnt(0)" ::: "memory");
        }
        __builtin_amdgcn_s_barrier();
        const u16* ab = &As[(tt&3)*ASZ];
        const u16* bb = &Bs[(tt&3)*BSZ];
        bf16x8 af[4], bfr[2];
        #pragma unroll
        for (int mf = 0; mf < 4; mf++)
            af[mf] = *(const bf16x8*)&ab[(wm + mf*16 + frow)*BK + cc];
        #pragma unroll
        for (int nf = 0; nf < 2; nf++)
            bfr[nf] = *(const bf16x8*)&bb[(wn + nf*16 + frow)*BK + cc];
        #pragma unroll
        for (int mf = 0; mf < 4; mf++)
            #pragma unroll
            for (int nf = 0; nf < 2; nf++)
                acc[mf][nf] = __builtin_amdgcn_mfma_f32_16x16x32_bf16(af[mf], bfr[nf], acc[mf][nf], 0, 0, 0);
        asm volatile("s_waitcnt lgkmcnt(0)" ::: "memory");
        __builtin_amdgcn_sched_barrier(0);
        __builtin_amdgcn_s_barrier();
    }
#undef STAGE1

    int r4 = (lane >> 4)*4, cEl = lane & 15;
    #pragma unroll
    for (int mf = 0; mf < 4; mf++) {
        #pragma unroll
        for (int r = 0; r < 4; r++) {
            int row = wm + mf*16 + r4 + r;
            if (row < valid) {
                size_t rbase = (size_t)(offset + m0 + row)*HP;
                #pragma unroll
                for (int nf = 0; nf < 2; nf++) {
                    int gcol = nt*BN + wn + nf*16 + cEl;
                    float v = 0.f;
                    if (gcol < H_) v = fast_gelu(acc[mf][nf][r] + b1all[e*H_ + gcol]);
                    heb[rbase + gcol] = f2bf(v);
                }
            }
        }
    }
}

__global__ __launch_bounds__(256, 3) void gemm2_kernel(
    const u16* __restrict__ heb, const u16* __restrict__ w2b,
    const float* __restrict__ b2all,
    const int* __restrict__ ci, const float* __restrict__ sw_,
    float* __restrict__ y)
{
    __shared__ u16 As[4*ASZ];
    __shared__ u16 Bs[4*BSZ];
    int x = blockIdx.x, yb = blockIdx.y;
    int e, mt, nt;
    if (yb < 16*16) {
        if (x == 7) return;
        e = x; mt = yb/16; nt = yb - mt*16;
    } else {
        e = 7; int yy = yb - 16*16; int s = yy/16; nt = yy - s*16; mt = x*2 + s;
    }
    int count = ci[CI_COUNT+e];
    int m0 = mt*BM;
    if (m0 >= count) return;
    int offset = ci[CI_OFF+e];
    int valid = min(BM, count - m0);

    int t = threadIdx.x, wid = t >> 6, lane = t & 63;
    int rl = lane >> 2;
    int swz = (rl ^ (rl >> 2)) & 3;
    int sc = (lane & 3) ^ swz;
    const u16* w2e = w2b + (size_t)e*D_*HP;

    int r0 = wid*32 + rl;
    int s0 = min(offset + m0 + r0, SLOTS-1);
    int s1 = min(offset + m0 + r0 + 16, SLOTS-1);
    const u16* aSrc0 = heb + (size_t)s0*HP + sc*8;
    const u16* aSrc1 = heb + (size_t)s1*HP + sc*8;
    int rb = wid*16 + rl;
    const u16* bSrc = w2e + (size_t)(nt*BN + rb)*HP + sc*8;
    u16* aD0 = &As[wid*1024];
    u16* aD1 = &As[wid*1024 + 512];
    u16* bD  = &Bs[wid*512];

    int wm = (wid >> 1)*64, wn = (wid & 1)*32;
    int frow = lane & 15, kgrp = lane >> 4;
    int cc = (kgrp ^ ((frow ^ (frow >> 2)) & 3)) * 8;
    f32x4 acc[4][2] = {};

#define STAGE2(tt) do { int _b=((tt)&3); int _ko=(tt)*BK; \
    gload_lds16(aSrc0+_ko, aD0+_b*ASZ); \
    gload_lds16(aSrc1+_ko, aD1+_b*ASZ); \
    gload_lds16(bSrc +_ko, bD +_b*BSZ); } while(0)

    STAGE2(0); STAGE2(1); STAGE2(2);
    constexpr int nIter = HP/BK;          // 44
    for (int tt = 0; tt < nIter; ++tt) {
        if (tt + 3 < nIter) {
            STAGE2(tt+3);
            asm volatile("s_waitcnt vmcnt(9)" ::: "memory");
        } else if (tt + 3 == nIter) {
            asm volatile("s_waitcnt vmcnt(6)" ::: "memory");
        } else if (tt + 2 == nIter) {
            asm volatile("s_waitcnt vmcnt(3)" ::: "memory");
        } else {
            asm volatile("s_waitcnt vmcnt(0)" ::: "memory");
        }
        __builtin_amdgcn_s_barrier();
        const u16* ab = &As[(tt&3)*ASZ];
        const u16* bb = &Bs[(tt&3)*BSZ];
        bf16x8 af[4], bfr[2];
        #pragma unroll
        for (int mf = 0; mf < 4; mf++)
            af[mf] = *(const bf16x8*)&ab[(wm + mf*16 + frow)*BK + cc];
        #pragma unroll
        for (int nf = 0; nf < 2; nf++)
            bfr[nf] = *(const bf16x8*)&bb[(wn + nf*16 + frow)*BK + cc];
        #pragma unroll
        for (int mf = 0; mf < 4; mf++)
            #pragma unroll
            for (int nf = 0; nf < 2; nf++)
                acc[mf][nf] = __builtin_amdgcn_mfma_f32_16x16x32_bf16(af[mf], bfr[nf], acc[mf][nf], 0, 0, 0);
        asm volatile("s_waitcnt lgkmcnt(0)" ::: "memory");
        __builtin_amdgcn_sched_barrier(0);
        __builtin_amdgcn_s_barrier();
    }
#undef STAGE2

    int r4 = (lane >> 4)*4, cEl = lane & 15;
    #pragma unroll
    for (int mf = 0; mf < 4; mf++) {
        #pragma unroll
        for (int r = 0; r < 4; r++) {
            int row = wm + mf*16 + r4 + r;
            if (row < valid) {
                int slot = offset + m0 + row;
                float w = sw_[slot];
                float* yrow = y + (size_t)slot*D_;
                #pragma unroll
                for (int nf = 0; nf < 2; nf++) {
                    int gcol = nt*BN + wn + nf*16 + cEl;
                    float v = acc[mf][nf][r] + b2all[e*D_ + gcol];
                    yrow[gcol] = w*v;
                }
            }
        }
    }
}

// ---------------- combine: out[n] = y[s0] + y[s1] + y[shared+n] ----------------
__global__ __launch_bounds__(256) void combine_kernel(
    const float* __restrict__ y, const int* __restrict__ tsl,
    float* __restrict__ out)
{
    int n = blockIdx.x;
    int t = threadIdx.x;
    int s0 = tsl[2*n], s1 = tsl[2*n+1];
    const float4* y0 = (const float4*)(y + (size_t)s0*D_);
    const float4* y1 = (const float4*)(y + (size_t)s1*D_);
    const float4* ys = (const float4*)(y + (size_t)(SHARED_BASE+n)*D_);
    float4 a = y0[t], b = y1[t], c = ys[t];
    float4 r;
    r.x = a.x + b.x + c.x;
    r.y = a.y + b.y + c.y;
    r.z = a.z + b.z + c.z;
    r.w = a.w + b.w + c.w;
    ((float4*)(out + (size_t)n*D_))[t] = r;
}

extern "C" void kernel_launch(void* const* d_in, const int* in_sizes, int n_in,
                              void* d_out, int out_size, void* d_ws, size_t ws_size,
                              hipStream_t stream)
{
    const float* x   = (const float*)d_in[0];
    const float* Wg  = (const float*)d_in[1];
    const float* W1  = (const float*)d_in[2];
    const float* b1  = (const float*)d_in[3];
    const float* W2  = (const float*)d_in[4];
    const float* b2  = (const float*)d_in[5];
    const float* Ws1 = (const float*)d_in[6];
    const float* bs1 = (const float*)d_in[7];
    const float* Ws2 = (const float*)d_in[8];
    const float* bs2 = (const float*)d_in[9];
    float* out = (float*)d_out;
    char* ws = (char*)d_ws;

    int*   ci    = (int*)(ws + WS_CTRL);
    int*   tidx  = (int*)(ws + WS_TIDX);
    float* tw    = (float*)(ws + WS_TW);
    float* probs = (float*)(ws + WS_PROB);
    float* lse2  = (float*)(ws + WS_LSE2);
    int*   stok  = (int*)(ws + WS_STOK);
    float* sw    = (float*)(ws + WS_SW);
    int*   tsl   = (int*)(ws + WS_TSL);
    float* b1all = (float*)(ws + WS_B1);
    float* b2all = (float*)(ws + WS_B2);
    u16*   xb    = (u16*)(ws + WS_XB);
    u16*   w1b   = (u16*)(ws + WS_W1B);
    u16*   w2b   = (u16*)(ws + WS_W2B);
    u16*   heb   = (u16*)(ws + WS_HEB);
    float* y     = (float*)(ws + WS_Y);

    convert_kernel<<<2048, 256, 0, stream>>>(W1, Ws1, W2, Ws2, b1, bs1, b2, bs2,
                                             w1b, w2b, b1all, b2all);
    router_kernel<<<NTOK/4, 256, 0, stream>>>(x, Wg, tidx, tw, probs, lse2, xb);
    finalize_kernel<<<1, 512, 0, stream>>>(tidx, tw, probs, lse2, ci, stok, sw, tsl, out);

    // expert -> XCD pinned: grid.x = 8 = #XCDs (linear%8 == blockIdx.x == expert)
    dim3 g1(8, 16*22 + 2*22);   // routed: 16mt x 22nt; shared: 2 stripes x 22nt (mt = x*2+s)
    gemm1_kernel<<<g1, 256, 0, stream>>>(xb, w1b, b1all, ci, stok, heb);
    dim3 g2(8, 16*16 + 2*16);   // routed: 16mt x 16nt; shared: 2 stripes x 16nt
    gemm2_kernel<<<g2, 256, 0, stream>>>(heb, w2b, b2all, ci, sw, y);
    combine_kernel<<<NTOK, 256, 0, stream>>>(y, tsl, out);
}

// Round 6
// 177.712 us; speedup vs baseline: 1.1168x; 1.1168x over previous
//
#include <hip/hip_runtime.h>
#include <hip/hip_bf16.h>
#include <math.h>

typedef unsigned short u16;
typedef __attribute__((ext_vector_type(8))) short bf16x8;
typedef __attribute__((ext_vector_type(4))) float f32x4;

constexpr int D_ = 1024;
constexpr int H_ = 1365;
constexpr int E_ = 7;
constexpr int NTOK = 2048;
constexpr int HP = 1408;          // H padded to multiple of 64
constexpr int NE = 8;             // 7 routed + 1 shared
constexpr int SHARED_BASE = 4096;
constexpr int SLOTS = 6144;

#define CI_COUNT 0
#define CI_OFF   8

constexpr size_t WS_CTRL = 0;
constexpr size_t WS_TIDX = 256;
constexpr size_t WS_TW   = WS_TIDX + (size_t)NTOK*2*4;
constexpr size_t WS_PROB = WS_TW   + (size_t)NTOK*2*4;
constexpr size_t WS_LSE2 = WS_PROB + (size_t)NTOK*8*4;
constexpr size_t WS_STOK = WS_LSE2 + (size_t)NTOK*4;
constexpr size_t WS_SW   = WS_STOK + (size_t)SLOTS*4;
constexpr size_t WS_B1   = WS_SW   + (size_t)SLOTS*4;
constexpr size_t WS_B2   = WS_B1   + (size_t)NE*H_*4;
constexpr size_t WS_XB   = ((WS_B2 + (size_t)NE*D_*4) + 255) & ~(size_t)255;
constexpr size_t WS_W1B  = WS_XB  + (size_t)NTOK*D_*2;
constexpr size_t WS_W2B  = WS_W1B + (size_t)NE*H_*D_*2;
constexpr size_t WS_HEB  = WS_W2B + (size_t)NE*D_*HP*2;

__device__ __forceinline__ u16 f2bf(float f) {
    __hip_bfloat16 h = __float2bfloat16(f);
    return __builtin_bit_cast(u16, h);
}

__device__ __forceinline__ void gload_lds16(const u16* g, u16* l) {
    __builtin_amdgcn_global_load_lds(
        (const __attribute__((address_space(1))) void*)g,
        (__attribute__((address_space(3))) void*)l, 16, 0, 0);
}

__device__ __forceinline__ uint4 pack8(float4 a, float4 b) {
    union { u16 h[8]; uint4 v; } u;
    u.h[0]=f2bf(a.x); u.h[1]=f2bf(a.y); u.h[2]=f2bf(a.z); u.h[3]=f2bf(a.w);
    u.h[4]=f2bf(b.x); u.h[5]=f2bf(b.y); u.h[6]=f2bf(b.z); u.h[7]=f2bf(b.w);
    return u.v;
}

// tanh-form GELU (|err| ~3e-3, below bf16 quantization of He)
__device__ __forceinline__ float fast_gelu(float v) {
    float u = 0.7978845608f * v * (1.f + 0.044715f * v * v);
    float e = __expf(2.f * u);
    float t = 1.f - 2.f / (e + 1.f);
    return 0.5f * v * (1.f + t);
}

// ================= GEMM cores: BM=128 BN=64 BK=64, 3-buf single-barrier =================
#define BM 128
#define BN 64
#define KSTEP 64
#define ATILE (BM*KSTEP)    // 8192 elems (16 KiB)
#define BTILE (BN*KSTEP)    // 4096 elems (8 KiB)
// LDS total: 3*(16+8) KiB = 72 KiB -> 2 blocks/CU

// He = gelu(X @ W1e^T + b1e): A rows gathered via stok (or identity for shared)
template<bool USE_STOK>
__device__ __forceinline__ void gemm1_body(u16* As, u16* Bs,
    const u16* xb, const u16* w1e, const float* b1e,
    const int* stok, int offset, int m0, int valid, int nt,
    u16* heb)
{
    int t = threadIdx.x, wid = t >> 6, lane = t & 63;
    int rl = lane >> 3, cl = lane & 7;
    int sg = cl ^ rl;                    // pre-swizzled source chunk (3-bit XOR, 128B rows)

    const u16* aP[4]; int dA[4];
    const u16* bP[2]; int dB[2];
    #pragma unroll
    for (int c = 0; c < 4; c++) {
        int arow = wid*32 + c*8 + rl;
        int ar = min(arow, valid-1);
        int tok = USE_STOK ? stok[offset + m0 + ar] : (m0 + ar);
        aP[c] = xb + (size_t)tok*D_ + sg*8;
        dA[c] = (wid*32 + c*8)*KSTEP;
    }
    #pragma unroll
    for (int c = 0; c < 2; c++) {
        int brow = wid*16 + c*8 + rl;
        int jg = min(nt*BN + brow, H_-1);
        bP[c] = w1e + (size_t)jg*D_ + sg*8;
        dB[c] = (wid*16 + c*8)*KSTEP;
    }

    int wm = (wid >> 1)*64, wn = (wid & 1)*32;
    int frow = lane & 15, kg = lane >> 4, f7 = frow & 7;
    f32x4 acc[4][2] = {};

    #pragma unroll
    for (int c = 0; c < 4; c++) gload_lds16(aP[c], As + dA[c]);
    #pragma unroll
    for (int c = 0; c < 2; c++) gload_lds16(bP[c], Bs + dB[c]);

    constexpr int nIter = D_/KSTEP;      // 16
    int cur = 0;
    for (int tt = 0; tt < nIter; ++tt) {
        if (tt + 1 < nIter) {
            int nb = (cur+1 == 3) ? 0 : cur+1;
            int ko = (tt+1)*KSTEP;
            #pragma unroll
            for (int c = 0; c < 4; c++) gload_lds16(aP[c]+ko, As + nb*ATILE + dA[c]);
            #pragma unroll
            for (int c = 0; c < 2; c++) gload_lds16(bP[c]+ko, Bs + nb*BTILE + dB[c]);
            asm volatile("s_waitcnt vmcnt(6)" ::: "memory");
        } else {
            asm volatile("s_waitcnt vmcnt(0)" ::: "memory");
        }
        __builtin_amdgcn_s_barrier();
        __builtin_amdgcn_sched_barrier(0);
        const u16* ab = As + cur*ATILE;
        const u16* bb = Bs + cur*BTILE;
        __builtin_amdgcn_s_setprio(1);
        #pragma unroll
        for (int s = 0; s < 2; s++) {
            int ch = ((s*4 + kg) ^ f7) * 8;
            bf16x8 af[4], bv[2];
            #pragma unroll
            for (int mf = 0; mf < 4; mf++) af[mf] = *(const bf16x8*)&ab[(wm+mf*16+frow)*KSTEP + ch];
            #pragma unroll
            for (int nf = 0; nf < 2; nf++) bv[nf] = *(const bf16x8*)&bb[(wn+nf*16+frow)*KSTEP + ch];
            #pragma unroll
            for (int mf = 0; mf < 4; mf++)
                #pragma unroll
                for (int nf = 0; nf < 2; nf++)
                    acc[mf][nf] = __builtin_amdgcn_mfma_f32_16x16x32_bf16(af[mf], bv[nf], acc[mf][nf], 0, 0, 0);
        }
        __builtin_amdgcn_s_setprio(0);
        cur = (cur+1 == 3) ? 0 : cur+1;
    }

    int r4 = (lane >> 4)*4, cEl = lane & 15;
    #pragma unroll
    for (int mf = 0; mf < 4; mf++) {
        #pragma unroll
        for (int r = 0; r < 4; r++) {
            int row = wm + mf*16 + r4 + r;
            if (row < valid) {
                size_t rbase = (size_t)(offset + m0 + row)*HP;
                #pragma unroll
                for (int nf = 0; nf < 2; nf++) {
                    int gcol = nt*BN + wn + nf*16 + cEl;
                    float v = 0.f;
                    if (gcol < H_) v = fast_gelu(acc[mf][nf][r] + b1e[gcol]);
                    heb[rbase + gcol] = f2bf(v);
                }
            }
        }
    }
}

// out contribution from He @ W2e^T + b2e.  MODE 0: plain store (shared expert, w=1);
// MODE 1: atomicAdd(out, w*v) (routed experts)
template<int MODE>
__device__ __forceinline__ void gemm2_body(u16* As, u16* Bs,
    const u16* heb, const u16* w2e, const float* b2e, const float* sw,
    int offset, int m0, int valid, int nt, float* out, const int* stok)
{
    int t = threadIdx.x, wid = t >> 6, lane = t & 63;
    int rl = lane >> 3, cl = lane & 7;
    int sg = cl ^ rl;

    const u16* aP[4]; int dA[4];
    const u16* bP[2]; int dB[2];
    #pragma unroll
    for (int c = 0; c < 4; c++) {
        int arow = wid*32 + c*8 + rl;
        int ar = min(arow, valid-1);
        int slot = offset + m0 + ar;
        aP[c] = heb + (size_t)slot*HP + sg*8;
        dA[c] = (wid*32 + c*8)*KSTEP;
    }
    #pragma unroll
    for (int c = 0; c < 2; c++) {
        int brow = wid*16 + c*8 + rl;
        int jg = nt*BN + brow;            // < 1024 always
        bP[c] = w2e + (size_t)jg*HP + sg*8;
        dB[c] = (wid*16 + c*8)*KSTEP;
    }

    int wm = (wid >> 1)*64, wn = (wid & 1)*32;
    int frow = lane & 15, kg = lane >> 4, f7 = frow & 7;
    f32x4 acc[4][2] = {};

    #pragma unroll
    for (int c = 0; c < 4; c++) gload_lds16(aP[c], As + dA[c]);
    #pragma unroll
    for (int c = 0; c < 2; c++) gload_lds16(bP[c], Bs + dB[c]);

    constexpr int nIter = HP/KSTEP;      // 22
    int cur = 0;
    for (int tt = 0; tt < nIter; ++tt) {
        if (tt + 1 < nIter) {
            int nb = (cur+1 == 3) ? 0 : cur+1;
            int ko = (tt+1)*KSTEP;
            #pragma unroll
            for (int c = 0; c < 4; c++) gload_lds16(aP[c]+ko, As + nb*ATILE + dA[c]);
            #pragma unroll
            for (int c = 0; c < 2; c++) gload_lds16(bP[c]+ko, Bs + nb*BTILE + dB[c]);
            asm volatile("s_waitcnt vmcnt(6)" ::: "memory");
        } else {
            asm volatile("s_waitcnt vmcnt(0)" ::: "memory");
        }
        __builtin_amdgcn_s_barrier();
        __builtin_amdgcn_sched_barrier(0);
        const u16* ab = As + cur*ATILE;
        const u16* bb = Bs + cur*BTILE;
        __builtin_amdgcn_s_setprio(1);
        #pragma unroll
        for (int s = 0; s < 2; s++) {
            int ch = ((s*4 + kg) ^ f7) * 8;
            bf16x8 af[4], bv[2];
            #pragma unroll
            for (int mf = 0; mf < 4; mf++) af[mf] = *(const bf16x8*)&ab[(wm+mf*16+frow)*KSTEP + ch];
            #pragma unroll
            for (int nf = 0; nf < 2; nf++) bv[nf] = *(const bf16x8*)&bb[(wn+nf*16+frow)*KSTEP + ch];
            #pragma unroll
            for (int mf = 0; mf < 4; mf++)
                #pragma unroll
                for (int nf = 0; nf < 2; nf++)
                    acc[mf][nf] = __builtin_amdgcn_mfma_f32_16x16x32_bf16(af[mf], bv[nf], acc[mf][nf], 0, 0, 0);
        }
        __builtin_amdgcn_s_setprio(0);
        cur = (cur+1 == 3) ? 0 : cur+1;
    }

    int r4 = (lane >> 4)*4, cEl = lane & 15;
    #pragma unroll
    for (int mf = 0; mf < 4; mf++) {
        #pragma unroll
        for (int r = 0; r < 4; r++) {
            int row = wm + mf*16 + r4 + r;
            if (row < valid) {
                if (MODE == 0) {
                    float* orow = out + (size_t)(m0 + row)*D_;
                    #pragma unroll
                    for (int nf = 0; nf < 2; nf++) {
                        int gcol = nt*BN + wn + nf*16 + cEl;
                        orow[gcol] = acc[mf][nf][r] + b2e[gcol];
                    }
                } else {
                    int slot = offset + m0 + row;
                    int tok = stok[slot];
                    float w = sw[slot];
                    #pragma unroll
                    for (int nf = 0; nf < 2; nf++) {
                        int gcol = nt*BN + wn + nf*16 + cEl;
                        atomicAdd(out + (size_t)tok*D_ + gcol, w*(acc[mf][nf][r] + b2e[gcol]));
                    }
                }
            }
        }
    }
}

// ================= finalize (256 threads): counts, offsets, losses, scatter =================
__device__ void finalize_body(char* smem,
    const int* tidx, const float* tw, const float* probs, const float* lse2,
    int* ci, int* stok, float* sw, float* out)
{
    int*   lt   = (int*)smem;               // 4096 ints (16 KiB)
    float* psum = (float*)(smem + 16384);   // 8
    float* lsum = (float*)(smem + 16384 + 32);
    int*   cntS = (int*)(smem + 16448);
    int*   offS = (int*)(smem + 16480);
    int t = threadIdx.x;
    if (t < 8) { psum[t] = 0.f; cntS[t] = 0; }
    if (t == 0) *lsum = 0.f;
    for (int i = t; i < NTOK*2; i += 256) lt[i] = tidx[i];
    for (int n = t; n < NTOK; n += 256) { stok[SHARED_BASE+n] = n; sw[SHARED_BASE+n] = 1.f; }
    __syncthreads();
    float lp[E_] = {}; float ll = 0.f;
    for (int n = t; n < NTOK; n += 256) {
        #pragma unroll
        for (int e = 0; e < E_; e++) lp[e] += probs[n*8+e];
        ll += lse2[n];
    }
    #pragma unroll
    for (int e = 0; e < E_; e++) atomicAdd(&psum[e], lp[e]);
    atomicAdd(lsum, ll);
    int wid = t >> 6, lane = t & 63;
    for (int e = wid; e < 7; e += 4) {
        int c = 0;
        for (int i = lane; i < NTOK*2; i += 64) c += (lt[i] == e) ? 1 : 0;
        #pragma unroll
        for (int m = 32; m >= 1; m >>= 1) c += __shfl_xor(c, m);
        if (lane == 0) cntS[e] = c;
    }
    __syncthreads();
    if (t == 0) {
        int o = 0;
        for (int e = 0; e < E_; e++) { offS[e] = o; o += cntS[e]; }
        offS[7] = SHARED_BASE; cntS[7] = NTOK;
        float la = 0.f;
        for (int e = 0; e < E_; e++)
            la += ((float)cntS[e] / (float)(NTOK*2)) * (psum[e] / (float)NTOK);
        out[(size_t)NTOK*D_]     = 0.01f * 7.f * la;
        out[(size_t)NTOK*D_ + 1] = 0.001f * (*lsum) / (float)NTOK;
        #pragma unroll
        for (int e = 0; e < 8; e++) { ci[CI_COUNT+e] = cntS[e]; ci[CI_OFF+e] = offS[e]; }
    }
    __syncthreads();
    for (int e = wid; e < 7; e += 4) {
        int base = offS[e], run = 0;
        for (int c0 = 0; c0 < NTOK*2; c0 += 64) {
            bool m = (lt[c0 + lane] == e);
            unsigned long long bal = __ballot(m);
            int pre = __popcll(bal & ((1ull << lane) - 1ull));
            if (m) {
                int i = c0 + lane;
                int s = base + run + pre;
                stok[s] = i >> 1; sw[s] = tw[i];
            }
            run += __popcll(bal);
        }
    }
}

// ================= k1: router (blocks 0..511) || W1+x-side convert (512..1023) ===========
__global__ __launch_bounds__(256) void prep_kernel(
    const float* __restrict__ x, const float* __restrict__ Wg,
    const float* __restrict__ W1, const float* __restrict__ Ws1,
    const float* __restrict__ b1, const float* __restrict__ bs1,
    int* __restrict__ tidx, float* __restrict__ tw,
    float* __restrict__ probs, float* __restrict__ lse2,
    u16* __restrict__ xb, u16* __restrict__ w1b, float* __restrict__ b1all)
{
    int b = blockIdx.x;
    if (b < 512) {
        int wid = threadIdx.x >> 6, lane = threadIdx.x & 63;
        int n = b*4 + wid;
        float p[E_] = {};
        const float* xr = x + (size_t)n*D_;
        u16* xbr = xb + (size_t)n*D_;
        #pragma unroll
        for (int j = 0; j < 4; j++) {
            int d0 = lane*4 + j*256;
            float4 xv = *(const float4*)(xr + d0);
            ushort4 h;
            h.x = f2bf(xv.x); h.y = f2bf(xv.y); h.z = f2bf(xv.z); h.w = f2bf(xv.w);
            *(ushort4*)(xbr + d0) = h;
            #pragma unroll
            for (int e = 0; e < E_; e++) {
                float4 wv = *(const float4*)(Wg + e*D_ + d0);
                p[e] += xv.x*wv.x + xv.y*wv.y + xv.z*wv.z + xv.w*wv.w;
            }
        }
        #pragma unroll
        for (int e = 0; e < E_; e++) {
            float v = p[e];
            #pragma unroll
            for (int m = 32; m >= 1; m >>= 1) v += __shfl_xor(v, m);
            p[e] = v;
        }
        if (lane == 0) {
            float mx = p[0];
            #pragma unroll
            for (int e = 1; e < E_; e++) mx = fmaxf(mx, p[e]);
            float pr[E_], sum = 0.f;
            #pragma unroll
            for (int e = 0; e < E_; e++) { pr[e] = __expf(p[e]-mx); sum += pr[e]; }
            float lse = mx + logf(sum);
            int i0 = 0;
            #pragma unroll
            for (int e = 1; e < E_; e++) if (p[e] > p[i0]) i0 = e;
            int i1 = -1;
            #pragma unroll
            for (int e = 0; e < E_; e++) if (e != i0 && (i1 < 0 || p[e] > p[i1])) i1 = e;
            float g = expf(p[i1] - p[i0]);
            tidx[n*2] = i0; tidx[n*2+1] = i1;
            tw[n*2] = 1.f/(1.f+g); tw[n*2+1] = g/(1.f+g);
            float inv = 1.f/sum;
            #pragma unroll
            for (int e = 0; e < E_; e++) probs[n*8+e] = pr[e]*inv;
            lse2[n] = lse*lse;
        }
        return;
    }
    // ---- W1 + biases convert ----
    const size_t G1 = (size_t)NE*H_*D_/8;
    const size_t W1FLAT = (size_t)7*H_*D_;
    const size_t total = G1 + (size_t)NE*H_;
    const size_t stride = (size_t)512*256;
    for (size_t i = (size_t)(b-512)*256 + threadIdx.x; i < total; i += stride) {
        if (i < G1) {
            size_t base = i*8;
            const float* src = (base < W1FLAT) ? (W1 + base) : (Ws1 + (base - W1FLAT));
            const float4* s = (const float4*)src;
            ((uint4*)w1b)[i] = pack8(s[0], s[1]);
        } else {
            size_t k = i - G1;
            size_t e = k/H_, j = k - e*H_;
            b1all[k] = (e < 7) ? b1[k] : bs1[j];
        }
    }
}

// ===== k2: finalize (block 0) || shared-expert GEMM1 (1..352) || W2 convert (353..865) ====
__global__ __launch_bounds__(256, 2) void k2_kernel(
    const float* __restrict__ W2, const float* __restrict__ Ws2,
    const float* __restrict__ b2, const float* __restrict__ bs2,
    u16* __restrict__ w2b, float* __restrict__ b2all,
    const int* __restrict__ tidx, const float* __restrict__ tw,
    const float* __restrict__ probs, const float* __restrict__ lse2,
    int* __restrict__ ci, int* __restrict__ stok, float* __restrict__ sw,
    float* __restrict__ out,
    const u16* __restrict__ xb, const u16* __restrict__ w1b,
    const float* __restrict__ b1all, u16* __restrict__ heb)
{
    __shared__ u16 As[3*ATILE];
    __shared__ u16 Bs[3*BTILE];
    int b = blockIdx.x;
    if (b == 0) {
        finalize_body((char*)As, tidx, tw, probs, lse2, ci, stok, sw, out);
        return;
    }
    if (b <= 352) {
        int tdx = b - 1;
        int mt = tdx/22, nt = tdx - mt*22;
        gemm1_body<false>(As, Bs, xb, w1b + (size_t)7*H_*D_, b1all + 7*H_,
                          nullptr, SHARED_BASE, mt*BM, BM, nt, heb);
        return;
    }
    // ---- W2 + b2 convert ----
    const size_t G2 = (size_t)NE*D_*HP/8;
    const size_t total = G2 + (size_t)NE*D_;
    const size_t stride = (size_t)513*256;
    for (size_t i = (size_t)(b-353)*256 + threadIdx.x; i < total; i += stride) {
        if (i < G2) {
            size_t base = i*8;
            size_t e = base/((size_t)D_*HP);
            size_t rr = base - e*(size_t)D_*HP;
            size_t drow = rr/HP, h0 = rr - drow*HP;
            const float* srow = (e < 7) ? (W2 + ((size_t)e*D_ + drow)*H_)
                                        : (Ws2 + drow*(size_t)H_);
            union { u16 h[8]; uint4 v; } u;
            #pragma unroll
            for (int q = 0; q < 8; q++) {
                size_t h = h0 + q;
                u.h[q] = (h < (size_t)H_) ? f2bf(srow[h]) : (u16)0;
            }
            ((uint4*)w2b)[i] = u.v;
        } else {
            size_t k = i - G2;
            size_t e = k/D_, j = k - e*D_;
            b2all[k] = (e < 7) ? b2[k] : bs2[j];
        }
    }
}

// ===== k3: routed GEMM1 (XCD-pinned, yb<352) || shared GEMM2 (yb>=352, spread) ====
__global__ __launch_bounds__(256, 2) void k3_kernel(
    const int* __restrict__ ci, const int* __restrict__ stok,
    const u16* __restrict__ xb, const u16* __restrict__ w1b,
    const float* __restrict__ b1all, u16* __restrict__ heb,
    const u16* __restrict__ w2b, const float* __restrict__ b2all,
    float* __restrict__ out)
{
    __shared__ u16 As[3*ATILE];
    __shared__ u16 Bs[3*BTILE];
    int x = blockIdx.x, yb = blockIdx.y;
    if (yb < 352) {
        if (x == 7) return;
        int e = x, mt = yb/22, nt = yb - mt*22;
        int count = ci[CI_COUNT+e];
        int m0 = mt*BM;
        if (m0 >= count) return;
        gemm1_body<true>(As, Bs, xb, w1b + (size_t)e*H_*D_, b1all + e*H_,
                         stok, ci[CI_OFF+e], m0, min(BM, count-m0), nt, heb);
    } else {
        int idx = (yb - 352)*8 + x;       // 0..255
        int mt = idx >> 4, nt = idx & 15;
        gemm2_body<0>(As, Bs, heb, w2b + (size_t)7*D_*HP, b2all + 7*D_,
                      nullptr, SHARED_BASE, mt*BM, BM, nt, out, nullptr);
    }
}

// ===== k4: routed GEMM2 (XCD-pinned), atomicAdd into out ====
__global__ __launch_bounds__(256, 2) void k4_kernel(
    const int* __restrict__ ci, const int* __restrict__ stok, const float* __restrict__ sw,
    const u16* __restrict__ heb, const u16* __restrict__ w2b,
    const float* __restrict__ b2all, float* __restrict__ out)
{
    __shared__ u16 As[3*ATILE];
    __shared__ u16 Bs[3*BTILE];
    int x = blockIdx.x;
    if (x == 7) return;
    int yb = blockIdx.y;
    int e = x, mt = yb >> 4, nt = yb & 15;
    int count = ci[CI_COUNT+e];
    int m0 = mt*BM;
    if (m0 >= count) return;
    gemm2_body<1>(As, Bs, heb, w2b + (size_t)e*D_*HP, b2all + e*D_,
                  sw, ci[CI_OFF+e], m0, min(BM, count-m0), nt, out, stok);
}

extern "C" void kernel_launch(void* const* d_in, const int* in_sizes, int n_in,
                              void* d_out, int out_size, void* d_ws, size_t ws_size,
                              hipStream_t stream)
{
    const float* x   = (const float*)d_in[0];
    const float* Wg  = (const float*)d_in[1];
    const float* W1  = (const float*)d_in[2];
    const float* b1  = (const float*)d_in[3];
    const float* W2  = (const float*)d_in[4];
    const float* b2  = (const float*)d_in[5];
    const float* Ws1 = (const float*)d_in[6];
    const float* bs1 = (const float*)d_in[7];
    const float* Ws2 = (const float*)d_in[8];
    const float* bs2 = (const float*)d_in[9];
    float* out = (float*)d_out;
    char* ws = (char*)d_ws;

    int*   ci    = (int*)(ws + WS_CTRL);
    int*   tidx  = (int*)(ws + WS_TIDX);
    float* tw    = (float*)(ws + WS_TW);
    float* probs = (float*)(ws + WS_PROB);
    float* lse2  = (float*)(ws + WS_LSE2);
    int*   stok  = (int*)(ws + WS_STOK);
    float* sw    = (float*)(ws + WS_SW);
    float* b1all = (float*)(ws + WS_B1);
    float* b2all = (float*)(ws + WS_B2);
    u16*   xb    = (u16*)(ws + WS_XB);
    u16*   w1b   = (u16*)(ws + WS_W1B);
    u16*   w2b   = (u16*)(ws + WS_W2B);
    u16*   heb   = (u16*)(ws + WS_HEB);

    // k1: router (512 blocks) || W1/x convert (512 blocks)
    prep_kernel<<<1024, 256, 0, stream>>>(x, Wg, W1, Ws1, b1, bs1,
                                          tidx, tw, probs, lse2, xb, w1b, b1all);
    // k2: finalize || shared-expert GEMM1 (352 tiles) || W2 convert (513 blocks)
    k2_kernel<<<866, 256, 0, stream>>>(W2, Ws2, b2, bs2, w2b, b2all,
                                       tidx, tw, probs, lse2, ci, stok, sw, out,
                                       xb, w1b, b1all, heb);
    // k3: routed GEMM1 (expert->XCD pinned) || shared GEMM2 (spread over XCDs)
    k3_kernel<<<dim3(8, 352 + 32), 256, 0, stream>>>(ci, stok, xb, w1b, b1all, heb,
                                                     w2b, b2all, out);
    // k4: routed GEMM2, weighted atomic accumulate into out
    k4_kernel<<<dim3(8, 256), 256, 0, stream>>>(ci, stok, sw, heb, w2b, b2all, out);
}